// Round 5
// baseline (165.219 us; speedup 1.0000x reference)
//
#include <hip/hip_runtime.h>
#include <hip/hip_bf16.h>
#include <stdint.h>

typedef __attribute__((ext_vector_type(8))) short short8;
typedef __attribute__((ext_vector_type(4))) float floatx4;

#define HD 64
#define D_IN 1024
#define TLEN 4096
#define NB 4
#define PPB 144    // M=128 t-tiles: sum_{t=0}^{31} ceil((2t+2)/8)
#define LDP 72     // padded stride for P buffer (bf16 elems), 144 B (16B-aligned)
#define SL2E 0.18033688011112042f   // (1/sqrt(64)) * log2(e), folded into k
#define WSZ 196608                  // 3*64*1024 bf16 elems (single weight copy)

__device__ __forceinline__ short f2bf(float f) {
    union { float f; uint32_t u; } v{f};
    uint32_t u = v.u;
    uint32_t r = (u + 0x7FFFu + ((u >> 16) & 1u)) >> 16;
    return (short)r;
}

__device__ __forceinline__ float bf2f(short s) {
    union { uint32_t u; float f; } v;
    v.u = ((uint32_t)(uint16_t)s) << 16;
    return v.f;
}

__device__ __forceinline__ uint32_t pk2(float a, float b) {
    __hip_bfloat162 h = __float22bfloat162_rn(float2{a, b});
    union { __hip_bfloat162 h; uint32_t u; } c{h};
    return c.u;
}

// async 16-B global->LDS copy (fire-and-forget, no VGPR round trip)
__device__ __forceinline__ void ld_lds16(const void* g, void* l) {
    __builtin_amdgcn_global_load_lds(
        (const __attribute__((address_space(1))) uint32_t*)g,
        (__attribute__((address_space(3))) uint32_t*)l, 16, 0, 0);
}

// ---------------- kernel 0: W -> fragment-major bf16 wt in ws ----------------
__global__ __launch_bounds__(256) void prep_w(const float* __restrict__ Wk,
                                              const float* __restrict__ Wq,
                                              const float* __restrict__ Wv,
                                              short* __restrict__ wt) {
    int i = blockIdx.x * 256 + threadIdx.x;      // 196608
    int j  = i & 7;
    int l  = (i >> 3) & 63;
    int ks = (i >> 9) & 1;
    int rest = i >> 10;
    int f  = rest % 12;
    int kt = rest / 12;
    int mat = f >> 2, nt = f & 3;
    int n = nt * 16 + (l & 15);
    int k = kt * 64 + ks * 32 + (l >> 4) * 8 + j;
    const float* W = (mat == 0) ? Wk : ((mat == 1) ? Wq : Wv);
    wt[i] = f2bf(W[(size_t)k * 64 + n]);
}

// ---------------- kernel 1: fused QKV projection, fully direct ----------------
// 32 rows/block (512 blocks). NO LDS, NO barriers: x A-fragments and W
// B-fragments both load global->VGPR. All 4 waves of a block read the same
// 8 KB x-slab per kt (L1-served after first touch); W fragments are per-wave
// (L2/L3-served, fragment-major from prep_w). Each wave is a self-contained
// load->pack->MFMA pipeline with no sync points; tests whether the staged
// global_load_lds + barrier-drain structure was proj's 42us floor.
__global__ __launch_bounds__(256) void proj(const float* __restrict__ x,
                                            const float* __restrict__ bk,
                                            const float* __restrict__ bq,
                                            const float* __restrict__ bv,
                                            const short* __restrict__ wt,
                                            short* __restrict__ ko,
                                            short* __restrict__ qo,
                                            short* __restrict__ vt) {
    int tid = threadIdx.x;
    int wave = tid >> 6, lane = tid & 63;
    int quad = lane >> 4, l16 = lane & 15;
    int row0 = blockIdx.x * 32;

    floatx4 acc[2][3];
#pragma unroll
    for (int mt = 0; mt < 2; mt++)
#pragma unroll
        for (int fi = 0; fi < 3; fi++) acc[mt][fi] = (floatx4){0.f, 0.f, 0.f, 0.f};

    // per-lane x base pointers (row = row0 + mt*16 + l16, col base = quad*8)
    const float* xb0 = x + (size_t)(row0 + l16) * D_IN + quad * 8;
    const float* xb1 = xb0 + (size_t)16 * D_IN;

    // per-wave weight fragment source offset (within a kt-chunk of 12288)
    const short* wv0 = wt + (size_t)(((wave * 3) * 2) * 64 + lane) * 8;

    auto wload = [&](int kt, short8 (&wf)[3][2]) {
#pragma unroll
        for (int fi = 0; fi < 3; fi++)
#pragma unroll
            for (int ks = 0; ks < 2; ks++)
                wf[fi][ks] = *reinterpret_cast<const short8*>(
                    wv0 + (size_t)kt * 12288 + (size_t)((fi * 2 + ks) * 64) * 8);
    };

    auto xload = [&](const float* xb, int kt, int ks) -> short8 {
        const float4* p = reinterpret_cast<const float4*>(xb + kt * 64 + ks * 32);
        float4 f0 = p[0], f1 = p[1];
        union { uint32_t u[4]; short8 s; } cv;
        cv.u[0] = pk2(f0.x, f0.y); cv.u[1] = pk2(f0.z, f0.w);
        cv.u[2] = pk2(f1.x, f1.y); cv.u[3] = pk2(f1.z, f1.w);
        return cv.s;
    };

    auto body = [&](int kt, short8 (&wcur)[3][2]) {
#pragma unroll
        for (int ks = 0; ks < 2; ks++) {
            short8 av[2];
            av[0] = xload(xb0, kt, ks);
            av[1] = xload(xb1, kt, ks);
#pragma unroll
            for (int fi = 0; fi < 3; fi++)
#pragma unroll
                for (int mt = 0; mt < 2; mt++)
                    acc[mt][fi] = __builtin_amdgcn_mfma_f32_16x16x32_bf16(av[mt], wcur[fi][ks], acc[mt][fi], 0, 0, 0);
        }
    };

    short8 wA[3][2], wB[3][2];
    wload(0, wA);
    for (int kt = 0; kt < 16; kt += 2) {
        wload(kt + 1, wB);          // in flight while computing kt
        body(kt, wA);
        if (kt + 2 < 16) wload(kt + 2, wA);  // in flight while computing kt+1
        body(kt + 1, wB);
    }

#pragma unroll
    for (int fi = 0; fi < 3; fi++) {
        int f = wave * 3 + fi;
        int mat = f >> 2, nt = f & 3;
        int col = nt * 16 + l16;
        const float* bias = (mat == 0) ? bk : ((mat == 1) ? bq : bv);
        float bb = bias[col];
#pragma unroll
        for (int mt = 0; mt < 2; mt++)
#pragma unroll
            for (int reg = 0; reg < 4; reg++) {
                float v = acc[mt][fi][reg] + bb;
                int row = row0 + mt * 16 + quad * 4 + reg;
                if (mat == 0) ko[(size_t)row * HD + col] = f2bf(v * SL2E);
                else if (mat == 1) qo[(size_t)row * HD + col] = f2bf(v);
                else {
                    int bt = row >> 12, tl = row & 4095;
                    vt[(size_t)bt * HD * TLEN + (size_t)col * TLEN + tl] = f2bf(v);
                }
            }
    }
}

// ---------------- kernel 2: flash causal attention, M=128, split-K ----------------
// (exact round-0 proven version)
template<int SPLIT>
__global__ __launch_bounds__(256) void attn_kern(const short* __restrict__ kb,
                                                 const short* __restrict__ qb,
                                                 const short* __restrict__ vtw,
                                                 short* __restrict__ pO,
                                                 float* __restrict__ pL,
                                                 float* __restrict__ out) {
    __shared__ short Ks[2][4096];   // 8 KB/buf: 64 s x 64 h, swizzled
    __shared__ short Vs[2][4096];   // 8 KB/buf: 64 h x 64 s, swizzled
    __shared__ short Ps[128 * LDP]; // P^T staging in [t][s] row-major

    int tid = threadIdx.x;
    int wave = tid >> 6, lane = tid & 63;
    int quad = lane >> 4, l16 = lane & 15;
    int wbase = tid & ~63;
    int batch = blockIdx.y;

    int tile, j0, j1, slot = 0, nparts = 1;
    if (SPLIT) {
        int bx = blockIdx.x;
        int t = 0, accb = 0;
        for (;;) { int p = (2 * t + 9) >> 3; if (bx < accb + p) break; accb += p; ++t; }
        tile = t;
        j0 = (bx - accb) * 8;
        int je = j0 + 8, lim = 2 * tile + 2;
        j1 = je < lim ? je : lim;
        slot = batch * PPB + bx;
        nparts = (2 * tile + 9) >> 3;
    } else {
        tile = 31 - blockIdx.x;
        j0 = 0; j1 = 2 * tile + 2;
    }
    int t0 = tile * 128;
    int jd = 2 * tile;               // diagonal pair starts at j = jd
    size_t base = (size_t)batch * TLEN * HD;
    const short* vbase = vtw + (size_t)batch * HD * TLEN;

    short8 kf[2][2];                 // [mt][ks] pre-scaled k rows as B-fragments
#pragma unroll
    for (int mt = 0; mt < 2; mt++) {
        int trow = t0 + wave * 32 + mt * 16 + l16;
#pragma unroll
        for (int ks = 0; ks < 2; ks++)
            kf[mt][ks] = *reinterpret_cast<const short8*>(kb + base + (size_t)trow * HD + ks * 32 + quad * 8);
    }

    floatx4 o_acc[2][4];
#pragma unroll
    for (int mt = 0; mt < 2; mt++)
#pragma unroll
        for (int ht = 0; ht < 4; ht++) o_acc[mt][ht] = (floatx4){0.f, 0.f, 0.f, 0.f};
    float l_p[2] = {0.f, 0.f};       // per-lane partial of l(t = l16 of mt tile)

    auto stage = [&](int j, int buf) {
        int s0 = j * 64;
#pragma unroll
        for (int it = 0; it < 2; it++) {
            int s = it * 256 + tid;
            int r = s >> 3, c = (s & 7) ^ (r & 7);
            ld_lds16(qb + base + (size_t)(s0 + r) * HD + c * 8,
                     &Ks[buf][(it * 256 + wbase) * 8]);
            ld_lds16(vbase + (size_t)r * TLEN + s0 + c * 8,
                     &Vs[buf][(it * 256 + wbase) * 8]);
        }
    };

    stage(j0, 0);
    for (int j = j0; j < j1; ++j) {
        int buf = (j - j0) & 1;
        __syncthreads();
        if (j + 1 < j1) stage(j + 1, buf ^ 1);

        // waves 0-1 are fully causal-masked on the second diagonal sub-tile
        if (j == jd + 1 && wave < 2) continue;

        // S^T = Qs(A) x kf(B): C[m=s][n=t], 16 MFMA, A-frags shared across mt
        floatx4 sacc[2][4];
#pragma unroll
        for (int mt = 0; mt < 2; mt++)
#pragma unroll
            for (int nt = 0; nt < 4; nt++) sacc[mt][nt] = (floatx4){0.f, 0.f, 0.f, 0.f};
#pragma unroll
        for (int ks = 0; ks < 2; ks++)
#pragma unroll
            for (int nt = 0; nt < 4; nt++) {
                int r = nt * 16 + l16, g = ks * 4 + quad;
                short8 a = *reinterpret_cast<const short8*>(
                    &Ks[buf][r * 64 + (g ^ (r & 7)) * 8]);
#pragma unroll
                for (int mt = 0; mt < 2; mt++)
                    sacc[mt][nt] = __builtin_amdgcn_mfma_f32_16x16x32_bf16(a, kf[mt][ks], sacc[mt][nt], 0, 0, 0);
            }

        // exp2 (k pre-scaled); causal mask only on the diagonal j-tiles
        float pv[2][4][4];
#pragma unroll
        for (int mt = 0; mt < 2; mt++)
#pragma unroll
            for (int nt = 0; nt < 4; nt++)
#pragma unroll
                for (int reg = 0; reg < 4; reg++)
                    pv[mt][nt][reg] = __builtin_amdgcn_exp2f(sacc[mt][nt][reg]);
        if (j >= jd) {
            int s0 = j * 64;
#pragma unroll
            for (int mt = 0; mt < 2; mt++) {
                int t_g = t0 + wave * 32 + mt * 16 + l16;
#pragma unroll
                for (int nt = 0; nt < 4; nt++) {
                    int s_g = s0 + nt * 16 + quad * 4;
#pragma unroll
                    for (int reg = 0; reg < 4; reg++)
                        if (s_g + reg > t_g) pv[mt][nt][reg] = 0.f;
                }
            }
        }
        // l partials (t = l16, pure per-lane adds) + packed P^T -> LDS (b64 writes)
#pragma unroll
        for (int mt = 0; mt < 2; mt++) {
            l_p[mt] += ((pv[mt][0][0] + pv[mt][0][1]) + (pv[mt][0][2] + pv[mt][0][3]))
                     + ((pv[mt][1][0] + pv[mt][1][1]) + (pv[mt][1][2] + pv[mt][1][3]))
                     + ((pv[mt][2][0] + pv[mt][2][1]) + (pv[mt][2][2] + pv[mt][2][3]))
                     + ((pv[mt][3][0] + pv[mt][3][1]) + (pv[mt][3][2] + pv[mt][3][3]));
#pragma unroll
            for (int nt = 0; nt < 4; nt++) {
                union { uint32_t u[2]; uint64_t q; } w;
                w.u[0] = pk2(pv[mt][nt][0], pv[mt][nt][1]);
                w.u[1] = pk2(pv[mt][nt][2], pv[mt][nt][3]);
                int row = wave * 32 + mt * 16 + l16;
                *reinterpret_cast<uint64_t*>(&Ps[row * LDP + nt * 16 + quad * 4]) = w.q;
            }
        }

        // O += P @ V : A = P (m=t=l16, k=s contiguous), B = V^T
#pragma unroll
        for (int ks = 0; ks < 2; ks++) {
            short8 a[2];
#pragma unroll
            for (int mt = 0; mt < 2; mt++)
                a[mt] = *reinterpret_cast<const short8*>(
                    &Ps[(wave * 32 + mt * 16 + l16) * LDP + ks * 32 + quad * 8]);
#pragma unroll
            for (int ht = 0; ht < 4; ht++) {
                int r = ht * 16 + l16, g = ks * 4 + quad;
                short8 b = *reinterpret_cast<const short8*>(
                    &Vs[buf][r * 64 + (g ^ (r & 7)) * 8]);
#pragma unroll
                for (int mt = 0; mt < 2; mt++)
                    o_acc[mt][ht] = __builtin_amdgcn_mfma_f32_16x16x32_bf16(a[mt], b, o_acc[mt][ht], 0, 0, 0);
            }
        }
    }

    // final l reduction across quads: every lane ends with L(t = l16 of its mt tile)
#pragma unroll
    for (int mt = 0; mt < 2; mt++) {
        l_p[mt] += __shfl_xor(l_p[mt], 16);
        l_p[mt] += __shfl_xor(l_p[mt], 32);
    }

    if (SPLIT && nparts > 1) {
        short* po = pO + (size_t)slot * 8192;
#pragma unroll
        for (int mt = 0; mt < 2; mt++)
#pragma unroll
            for (int ht = 0; ht < 4; ht++)
#pragma unroll
                for (int reg = 0; reg < 4; reg++) {
                    int lr = wave * 32 + mt * 16 + quad * 4 + reg;
                    po[lr * 64 + ht * 16 + l16] = f2bf(o_acc[mt][ht][reg]);
                }
        if (quad == 0) {
#pragma unroll
            for (int mt = 0; mt < 2; mt++)
                pL[(size_t)slot * 128 + wave * 32 + mt * 16 + l16] = l_p[mt];
        }
    } else {
#pragma unroll
        for (int mt = 0; mt < 2; mt++) {
            // move L to the o_acc row layout: row t_loc = quad*4+reg needs L from lane l16=t_loc
#pragma unroll
            for (int reg = 0; reg < 4; reg++) {
                float L = __shfl(l_p[mt], quad * 4 + reg, 64);
                float inv = 1.0f / L;
                int t = t0 + wave * 32 + mt * 16 + quad * 4 + reg;
#pragma unroll
                for (int ht = 0; ht < 4; ht++)
                    out[base + (size_t)t * HD + ht * 16 + l16] = o_acc[mt][ht][reg] * inv;
            }
        }
    }
}

// ---------------- kernel 3: combine split-K partials (bf16, coalesced) ----------------
// Covers tiles 4..31 (nparts >= 2); tiles 0..3 were written directly by attn.
// Row-quartered (grid.z = 4) to kill the tile-31 straggler block (~300 KB serial).
__global__ __launch_bounds__(256) void attn_combine(const short* __restrict__ pO,
                                                    const float* __restrict__ pL,
                                                    float* __restrict__ out) {
    int tile = blockIdx.x + 4, batch = blockIdx.y, rq = blockIdx.z;
    int nparts = (2 * tile + 9) >> 3;
    int a = tile >> 2, r = tile & 3;
    int slot0 = batch * PPB + 2 * a * (a + 1) + r * (a + 1);
    int t = threadIdx.x;
    int off = rq * 2048 + t * 8;      // 8 contiguous bf16 per thread, 32 rows/block
    int row = off >> 6;
    int col0 = off & 63;

    float L = 0.f;
    float acc[8];
#pragma unroll
    for (int i = 0; i < 8; i++) acc[i] = 0.f;

    for (int p = 0; p < nparts; ++p) {
        int slot = slot0 + p;
        L += pL[(size_t)slot * 128 + row];
        short8 v = *reinterpret_cast<const short8*>(pO + (size_t)slot * 8192 + off);
#pragma unroll
        for (int i = 0; i < 8; i++) acc[i] += bf2f(v[i]);
    }
    float inv = 1.0f / L;
    float4* dstp = reinterpret_cast<float4*>(out + (size_t)batch * TLEN * HD +
                                             (size_t)(tile * 128 + row) * HD + col0);
#pragma unroll
    for (int c = 0; c < 2; c++) {
        float4 v;
        v.x = acc[c * 4 + 0] * inv; v.y = acc[c * 4 + 1] * inv;
        v.z = acc[c * 4 + 2] * inv; v.w = acc[c * 4 + 3] * inv;
        dstp[c] = v;
    }
}

extern "C" void kernel_launch(void* const* d_in, const int* in_sizes, int n_in,
                              void* d_out, int out_size, void* d_ws, size_t ws_size,
                              hipStream_t stream) {
    const float* x  = (const float*)d_in[0];
    const float* Wk = (const float*)d_in[1];
    const float* bk = (const float*)d_in[2];
    const float* Wq = (const float*)d_in[3];
    const float* bq = (const float*)d_in[4];
    const float* Wv = (const float*)d_in[5];
    const float* bv = (const float*)d_in[6];
    float* out = (float*)d_out;

    const size_t nrow = (size_t)NB * TLEN;            // 16384
    short* ko = (short*)d_ws;                         // bf16 k (pre-scaled)      2 MB
    short* qo = ko + nrow * HD;                       // bf16 q                   2 MB
    short* vt = qo + nrow * HD;                       // bf16 v^T [4][64][4096]   2 MB
    short* wt = vt + nrow * HD;                       // bf16 wt frag-major       384 KB
    short* pO = wt + WSZ;                             // bf16 partial O [4*144][128][64]
    float* pL = (float*)(pO + (size_t)NB * PPB * 8192); // partial l [4*144][128]
    size_t need = (size_t)((char*)(pL + (size_t)NB * PPB * 128) - (char*)d_ws);

    prep_w<<<768, 256, 0, stream>>>(Wk, Wq, Wv, wt);
    proj<<<512, 256, 0, stream>>>(x, bk, bq, bv, wt, ko, qo, vt);
    if (ws_size >= need) {
        attn_kern<1><<<dim3(PPB, NB), 256, 0, stream>>>(ko, qo, vt, pO, pL, out);
        attn_combine<<<dim3(28, NB, 4), 256, 0, stream>>>(pO, pL, out);
    } else {
        attn_kern<0><<<dim3(32, NB), 256, 0, stream>>>(ko, qo, vt, nullptr, nullptr, out);
    }
}

// Round 6
// 148.944 us; speedup vs baseline: 1.1093x; 1.1093x over previous
//
#include <hip/hip_runtime.h>
#include <hip/hip_bf16.h>
#include <stdint.h>

typedef __attribute__((ext_vector_type(8))) short short8;
typedef __attribute__((ext_vector_type(4))) float floatx4;

#define HD 64
#define D_IN 1024
#define TLEN 4096
#define NB 4
#define PPB 144    // M=128 t-tiles: sum_{t=0}^{31} ceil((2t+2)/8)
#define LDP 72     // padded stride for P buffer (bf16 elems), 144 B (16B-aligned)
#define SL2E 0.18033688011112042f   // (1/sqrt(64)) * log2(e), folded into k
#define WSZ 196608                  // 3*64*1024 bf16 elems (single weight copy)

__device__ __forceinline__ short f2bf(float f) {
    union { float f; uint32_t u; } v{f};
    uint32_t u = v.u;
    uint32_t r = (u + 0x7FFFu + ((u >> 16) & 1u)) >> 16;
    return (short)r;
}

__device__ __forceinline__ float bf2f(short s) {
    union { uint32_t u; float f; } v;
    v.u = ((uint32_t)(uint16_t)s) << 16;
    return v.f;
}

__device__ __forceinline__ uint32_t pk2(float a, float b) {
    __hip_bfloat162 h = __float22bfloat162_rn(float2{a, b});
    union { __hip_bfloat162 h; uint32_t u; } c{h};
    return c.u;
}

// async 16-B global->LDS copy (fire-and-forget, no VGPR round trip)
__device__ __forceinline__ void ld_lds16(const void* g, void* l) {
    __builtin_amdgcn_global_load_lds(
        (const __attribute__((address_space(1))) uint32_t*)g,
        (__attribute__((address_space(3))) uint32_t*)l, 16, 0, 0);
}

// ---------------- kernel 0: W -> fragment-major bf16 wt in ws ----------------
__global__ __launch_bounds__(256) void prep_w(const float* __restrict__ Wk,
                                              const float* __restrict__ Wq,
                                              const float* __restrict__ Wv,
                                              short* __restrict__ wt) {
    int i = blockIdx.x * 256 + threadIdx.x;      // 196608
    int j  = i & 7;
    int l  = (i >> 3) & 63;
    int ks = (i >> 9) & 1;
    int rest = i >> 10;
    int f  = rest % 12;
    int kt = rest / 12;
    int mat = f >> 2, nt = f & 3;
    int n = nt * 16 + (l & 15);
    int k = kt * 64 + ks * 32 + (l >> 4) * 8 + j;
    const float* W = (mat == 0) ? Wk : ((mat == 1) ? Wq : Wv);
    wt[i] = f2bf(W[(size_t)k * 64 + n]);
}

// ---------------- kernel 1: fused QKV projection, deep-pipelined ----------------
// 32 rows/block (512 blocks). x staged via global_load_lds into a 4-buffer
// ring (8 KB each), prefetch distance 3; W direct global->VGPR (R4-neutral).
// Counted vmcnt (steady state 8 = stage kt+2, kt+3 and W kt+1 stay in flight)
// and ONE barrier per iteration (barrier-A implies all waves finished
// compute(kt-1) before anyone overwrites ring slot (kt+3)&3). The queue is
// never drained mid-loop -- attacks the ~10 B/cyc/CU latency-throttled
// service rate that pinned proj at 42us across R0-R5.
__global__ __launch_bounds__(256) void proj(const float* __restrict__ x,
                                            const float* __restrict__ bk,
                                            const float* __restrict__ bq,
                                            const float* __restrict__ bv,
                                            const short* __restrict__ wt,
                                            short* __restrict__ ko,
                                            short* __restrict__ qo,
                                            short* __restrict__ vt) {
    __shared__ float xs[4][2048];   // 4-deep ring, 8 KB each

    int tid = threadIdx.x;
    int wave = tid >> 6, lane = tid & 63;
    int quad = lane >> 4, l16 = lane & 15;
    int row0 = blockIdx.x * 32;
    int wbase = tid & ~63;

    floatx4 acc[2][3];
#pragma unroll
    for (int mt = 0; mt < 2; mt++)
#pragma unroll
        for (int fi = 0; fi < 3; fi++) acc[mt][fi] = (floatx4){0.f, 0.f, 0.f, 0.f};

    auto stage = [&](int kt, int buf) {
#pragma unroll
        for (int it = 0; it < 2; it++) {
            int s = it * 256 + tid;
            int r = s >> 4, p = s & 15;
            int c = (((p >> 1) ^ (r & 7)) << 1) | (p & 1);
            ld_lds16(x + (size_t)(row0 + r) * D_IN + kt * 64 + c * 4,
                     &xs[buf][(it * 256 + wbase) * 4]);
        }
    };

    // per-wave weight fragment source offset (within a kt-chunk of 12288)
    const short* wv0 = wt + (size_t)(((wave * 3) * 2) * 64 + lane) * 8;

    auto wload = [&](int kt, short8 (&wf)[3][2]) {
#pragma unroll
        for (int fi = 0; fi < 3; fi++)
#pragma unroll
            for (int ks = 0; ks < 2; ks++)
                wf[fi][ks] = *reinterpret_cast<const short8*>(
                    wv0 + (size_t)kt * 12288 + (size_t)((fi * 2 + ks) * 64) * 8);
    };

    auto body = [&](int kt, short8 (&wcur)[3][2]) {
        int buf = kt & 3;
#pragma unroll
        for (int ks = 0; ks < 2; ks++) {
            short8 av[2];
#pragma unroll
            for (int mt = 0; mt < 2; mt++) {
                int r = mt * 16 + l16;
                int g = ks * 4 + quad;
                const float4* pp = reinterpret_cast<const float4*>(
                    &xs[buf][r * 64 + ((g ^ (r & 7)) << 1) * 4]);
                float4 f0 = pp[0], f1 = pp[1];
                union { uint32_t u[4]; short8 s; } cv;
                cv.u[0] = pk2(f0.x, f0.y); cv.u[1] = pk2(f0.z, f0.w);
                cv.u[2] = pk2(f1.x, f1.y); cv.u[3] = pk2(f1.z, f1.w);
                av[mt] = cv.s;
            }
#pragma unroll
            for (int fi = 0; fi < 3; fi++)
#pragma unroll
                for (int mt = 0; mt < 2; mt++)
                    acc[mt][fi] = __builtin_amdgcn_mfma_f32_16x16x32_bf16(av[mt], wcur[fi][ks], acc[mt][fi], 0, 0, 0);
        }
    };

    short8 wA[3][2], wB[3][2];
    // prologue: W0 first (FIFO position matters for vmcnt math), then 3 stages
    wload(0, wA);
    stage(0, 0); stage(1, 1); stage(2, 2);

    auto step = [&](int kt, short8 (&wcur)[3][2], short8 (&wnxt)[3][2]) {
        wload(kt + 1, wnxt);                       // 6 vm loads, 1-iter flight
        // steady FIFO here: [s(kt+1),W(kt),s(kt+2),W(kt+1)] = 16 outstanding;
        // vmcnt(8) => W(kt)+s(kt) complete, leaves s(kt+2),s(kt+3)... in flight
        asm volatile("s_waitcnt vmcnt(8)" ::: "memory");
        __builtin_amdgcn_s_barrier();              // buffer kt ready, slot (kt+3)&3 free
        if (kt + 3 < 16) stage(kt + 3, (kt + 3) & 3);
        body(kt, wcur);
    };

    for (int kt2 = 0; kt2 < 14; kt2 += 2) {
        step(kt2, wA, wB);
        step(kt2 + 1, wB, wA);
    }
    // kt = 14: outstanding [s15, W14, W15] after wload -> vmcnt(6) = W14+s14 done
    wload(15, wB);
    asm volatile("s_waitcnt vmcnt(6)" ::: "memory");
    __builtin_amdgcn_s_barrier();
    body(14, wA);
    // kt = 15
    asm volatile("s_waitcnt vmcnt(0)" ::: "memory");
    __builtin_amdgcn_s_barrier();
    body(15, wB);

#pragma unroll
    for (int fi = 0; fi < 3; fi++) {
        int f = wave * 3 + fi;
        int mat = f >> 2, nt = f & 3;
        int col = nt * 16 + l16;
        const float* bias = (mat == 0) ? bk : ((mat == 1) ? bq : bv);
        float bb = bias[col];
#pragma unroll
        for (int mt = 0; mt < 2; mt++)
#pragma unroll
            for (int reg = 0; reg < 4; reg++) {
                float v = acc[mt][fi][reg] + bb;
                int row = row0 + mt * 16 + quad * 4 + reg;
                if (mat == 0) ko[(size_t)row * HD + col] = f2bf(v * SL2E);
                else if (mat == 1) qo[(size_t)row * HD + col] = f2bf(v);
                else {
                    int bt = row >> 12, tl = row & 4095;
                    vt[(size_t)bt * HD * TLEN + (size_t)col * TLEN + tl] = f2bf(v);
                }
            }
    }
}

// ---------------- kernel 2: flash causal attention, M=128, split-K ----------------
// (exact round-0 proven version)
template<int SPLIT>
__global__ __launch_bounds__(256) void attn_kern(const short* __restrict__ kb,
                                                 const short* __restrict__ qb,
                                                 const short* __restrict__ vtw,
                                                 short* __restrict__ pO,
                                                 float* __restrict__ pL,
                                                 float* __restrict__ out) {
    __shared__ short Ks[2][4096];   // 8 KB/buf: 64 s x 64 h, swizzled
    __shared__ short Vs[2][4096];   // 8 KB/buf: 64 h x 64 s, swizzled
    __shared__ short Ps[128 * LDP]; // P^T staging in [t][s] row-major

    int tid = threadIdx.x;
    int wave = tid >> 6, lane = tid & 63;
    int quad = lane >> 4, l16 = lane & 15;
    int wbase = tid & ~63;
    int batch = blockIdx.y;

    int tile, j0, j1, slot = 0, nparts = 1;
    if (SPLIT) {
        int bx = blockIdx.x;
        int t = 0, accb = 0;
        for (;;) { int p = (2 * t + 9) >> 3; if (bx < accb + p) break; accb += p; ++t; }
        tile = t;
        j0 = (bx - accb) * 8;
        int je = j0 + 8, lim = 2 * tile + 2;
        j1 = je < lim ? je : lim;
        slot = batch * PPB + bx;
        nparts = (2 * tile + 9) >> 3;
    } else {
        tile = 31 - blockIdx.x;
        j0 = 0; j1 = 2 * tile + 2;
    }
    int t0 = tile * 128;
    int jd = 2 * tile;               // diagonal pair starts at j = jd
    size_t base = (size_t)batch * TLEN * HD;
    const short* vbase = vtw + (size_t)batch * HD * TLEN;

    short8 kf[2][2];                 // [mt][ks] pre-scaled k rows as B-fragments
#pragma unroll
    for (int mt = 0; mt < 2; mt++) {
        int trow = t0 + wave * 32 + mt * 16 + l16;
#pragma unroll
        for (int ks = 0; ks < 2; ks++)
            kf[mt][ks] = *reinterpret_cast<const short8*>(kb + base + (size_t)trow * HD + ks * 32 + quad * 8);
    }

    floatx4 o_acc[2][4];
#pragma unroll
    for (int mt = 0; mt < 2; mt++)
#pragma unroll
        for (int ht = 0; ht < 4; ht++) o_acc[mt][ht] = (floatx4){0.f, 0.f, 0.f, 0.f};
    float l_p[2] = {0.f, 0.f};       // per-lane partial of l(t = l16 of mt tile)

    auto stage = [&](int j, int buf) {
        int s0 = j * 64;
#pragma unroll
        for (int it = 0; it < 2; it++) {
            int s = it * 256 + tid;
            int r = s >> 3, c = (s & 7) ^ (r & 7);
            ld_lds16(qb + base + (size_t)(s0 + r) * HD + c * 8,
                     &Ks[buf][(it * 256 + wbase) * 8]);
            ld_lds16(vbase + (size_t)r * TLEN + s0 + c * 8,
                     &Vs[buf][(it * 256 + wbase) * 8]);
        }
    };

    stage(j0, 0);
    for (int j = j0; j < j1; ++j) {
        int buf = (j - j0) & 1;
        __syncthreads();
        if (j + 1 < j1) stage(j + 1, buf ^ 1);

        // waves 0-1 are fully causal-masked on the second diagonal sub-tile
        if (j == jd + 1 && wave < 2) continue;

        // S^T = Qs(A) x kf(B): C[m=s][n=t], 16 MFMA, A-frags shared across mt
        floatx4 sacc[2][4];
#pragma unroll
        for (int mt = 0; mt < 2; mt++)
#pragma unroll
            for (int nt = 0; nt < 4; nt++) sacc[mt][nt] = (floatx4){0.f, 0.f, 0.f, 0.f};
#pragma unroll
        for (int ks = 0; ks < 2; ks++)
#pragma unroll
            for (int nt = 0; nt < 4; nt++) {
                int r = nt * 16 + l16, g = ks * 4 + quad;
                short8 a = *reinterpret_cast<const short8*>(
                    &Ks[buf][r * 64 + (g ^ (r & 7)) * 8]);
#pragma unroll
                for (int mt = 0; mt < 2; mt++)
                    sacc[mt][nt] = __builtin_amdgcn_mfma_f32_16x16x32_bf16(a, kf[mt][ks], sacc[mt][nt], 0, 0, 0);
            }

        // exp2 (k pre-scaled); causal mask only on the diagonal j-tiles
        float pv[2][4][4];
#pragma unroll
        for (int mt = 0; mt < 2; mt++)
#pragma unroll
            for (int nt = 0; nt < 4; nt++)
#pragma unroll
                for (int reg = 0; reg < 4; reg++)
                    pv[mt][nt][reg] = __builtin_amdgcn_exp2f(sacc[mt][nt][reg]);
        if (j >= jd) {
            int s0 = j * 64;
#pragma unroll
            for (int mt = 0; mt < 2; mt++) {
                int t_g = t0 + wave * 32 + mt * 16 + l16;
#pragma unroll
                for (int nt = 0; nt < 4; nt++) {
                    int s_g = s0 + nt * 16 + quad * 4;
#pragma unroll
                    for (int reg = 0; reg < 4; reg++)
                        if (s_g + reg > t_g) pv[mt][nt][reg] = 0.f;
                }
            }
        }
        // l partials (t = l16, pure per-lane adds) + packed P^T -> LDS (b64 writes)
#pragma unroll
        for (int mt = 0; mt < 2; mt++) {
            l_p[mt] += ((pv[mt][0][0] + pv[mt][0][1]) + (pv[mt][0][2] + pv[mt][0][3]))
                     + ((pv[mt][1][0] + pv[mt][1][1]) + (pv[mt][1][2] + pv[mt][1][3]))
                     + ((pv[mt][2][0] + pv[mt][2][1]) + (pv[mt][2][2] + pv[mt][2][3]))
                     + ((pv[mt][3][0] + pv[mt][3][1]) + (pv[mt][3][2] + pv[mt][3][3]));
#pragma unroll
            for (int nt = 0; nt < 4; nt++) {
                union { uint32_t u[2]; uint64_t q; } w;
                w.u[0] = pk2(pv[mt][nt][0], pv[mt][nt][1]);
                w.u[1] = pk2(pv[mt][nt][2], pv[mt][nt][3]);
                int row = wave * 32 + mt * 16 + l16;
                *reinterpret_cast<uint64_t*>(&Ps[row * LDP + nt * 16 + quad * 4]) = w.q;
            }
        }

        // O += P @ V : A = P (m=t=l16, k=s contiguous), B = V^T
#pragma unroll
        for (int ks = 0; ks < 2; ks++) {
            short8 a[2];
#pragma unroll
            for (int mt = 0; mt < 2; mt++)
                a[mt] = *reinterpret_cast<const short8*>(
                    &Ps[(wave * 32 + mt * 16 + l16) * LDP + ks * 32 + quad * 8]);
#pragma unroll
            for (int ht = 0; ht < 4; ht++) {
                int r = ht * 16 + l16, g = ks * 4 + quad;
                short8 b = *reinterpret_cast<const short8*>(
                    &Vs[buf][r * 64 + (g ^ (r & 7)) * 8]);
#pragma unroll
                for (int mt = 0; mt < 2; mt++)
                    o_acc[mt][ht] = __builtin_amdgcn_mfma_f32_16x16x32_bf16(a[mt], b, o_acc[mt][ht], 0, 0, 0);
            }
        }
    }

    // final l reduction across quads: every lane ends with L(t = l16 of its mt tile)
#pragma unroll
    for (int mt = 0; mt < 2; mt++) {
        l_p[mt] += __shfl_xor(l_p[mt], 16);
        l_p[mt] += __shfl_xor(l_p[mt], 32);
    }

    if (SPLIT && nparts > 1) {
        short* po = pO + (size_t)slot * 8192;
#pragma unroll
        for (int mt = 0; mt < 2; mt++)
#pragma unroll
            for (int ht = 0; ht < 4; ht++)
#pragma unroll
                for (int reg = 0; reg < 4; reg++) {
                    int lr = wave * 32 + mt * 16 + quad * 4 + reg;
                    po[lr * 64 + ht * 16 + l16] = f2bf(o_acc[mt][ht][reg]);
                }
        if (quad == 0) {
#pragma unroll
            for (int mt = 0; mt < 2; mt++)
                pL[(size_t)slot * 128 + wave * 32 + mt * 16 + l16] = l_p[mt];
        }
    } else {
#pragma unroll
        for (int mt = 0; mt < 2; mt++) {
            // move L to the o_acc row layout: row t_loc = quad*4+reg needs L from lane l16=t_loc
#pragma unroll
            for (int reg = 0; reg < 4; reg++) {
                float L = __shfl(l_p[mt], quad * 4 + reg, 64);
                float inv = 1.0f / L;
                int t = t0 + wave * 32 + mt * 16 + quad * 4 + reg;
#pragma unroll
                for (int ht = 0; ht < 4; ht++)
                    out[base + (size_t)t * HD + ht * 16 + l16] = o_acc[mt][ht][reg] * inv;
            }
        }
    }
}

// ---------------- kernel 3: combine split-K partials (bf16, coalesced) ----------------
// Covers tiles 4..31 (nparts >= 2); tiles 0..3 were written directly by attn.
// Row-quartered (grid.z = 4) to kill the tile-31 straggler block (~300 KB serial).
__global__ __launch_bounds__(256) void attn_combine(const short* __restrict__ pO,
                                                    const float* __restrict__ pL,
                                                    float* __restrict__ out) {
    int tile = blockIdx.x + 4, batch = blockIdx.y, rq = blockIdx.z;
    int nparts = (2 * tile + 9) >> 3;
    int a = tile >> 2, r = tile & 3;
    int slot0 = batch * PPB + 2 * a * (a + 1) + r * (a + 1);
    int t = threadIdx.x;
    int off = rq * 2048 + t * 8;      // 8 contiguous bf16 per thread, 32 rows/block
    int row = off >> 6;
    int col0 = off & 63;

    float L = 0.f;
    float acc[8];
#pragma unroll
    for (int i = 0; i < 8; i++) acc[i] = 0.f;

    for (int p = 0; p < nparts; ++p) {
        int slot = slot0 + p;
        L += pL[(size_t)slot * 128 + row];
        short8 v = *reinterpret_cast<const short8*>(pO + (size_t)slot * 8192 + off);
#pragma unroll
        for (int i = 0; i < 8; i++) acc[i] += bf2f(v[i]);
    }
    float inv = 1.0f / L;
    float4* dstp = reinterpret_cast<float4*>(out + (size_t)batch * TLEN * HD +
                                             (size_t)(tile * 128 + row) * HD + col0);
#pragma unroll
    for (int c = 0; c < 2; c++) {
        float4 v;
        v.x = acc[c * 4 + 0] * inv; v.y = acc[c * 4 + 1] * inv;
        v.z = acc[c * 4 + 2] * inv; v.w = acc[c * 4 + 3] * inv;
        dstp[c] = v;
    }
}

extern "C" void kernel_launch(void* const* d_in, const int* in_sizes, int n_in,
                              void* d_out, int out_size, void* d_ws, size_t ws_size,
                              hipStream_t stream) {
    const float* x  = (const float*)d_in[0];
    const float* Wk = (const float*)d_in[1];
    const float* bk = (const float*)d_in[2];
    const float* Wq = (const float*)d_in[3];
    const float* bq = (const float*)d_in[4];
    const float* Wv = (const float*)d_in[5];
    const float* bv = (const float*)d_in[6];
    float* out = (float*)d_out;

    const size_t nrow = (size_t)NB * TLEN;            // 16384
    short* ko = (short*)d_ws;                         // bf16 k (pre-scaled)      2 MB
    short* qo = ko + nrow * HD;                       // bf16 q                   2 MB
    short* vt = qo + nrow * HD;                       // bf16 v^T [4][64][4096]   2 MB
    short* wt = vt + nrow * HD;                       // bf16 wt frag-major       384 KB
    short* pO = wt + WSZ;                             // bf16 partial O [4*144][128][64]
    float* pL = (float*)(pO + (size_t)NB * PPB * 8192); // partial l [4*144][128]
    size_t need = (size_t)((char*)(pL + (size_t)NB * PPB * 128) - (char*)d_ws);

    prep_w<<<768, 256, 0, stream>>>(Wk, Wq, Wv, wt);
    proj<<<512, 256, 0, stream>>>(x, bk, bq, bv, wt, ko, qo, vt);
    if (ws_size >= need) {
        attn_kern<1><<<dim3(PPB, NB), 256, 0, stream>>>(ko, qo, vt, pO, pL, out);
        attn_combine<<<dim3(28, NB, 4), 256, 0, stream>>>(pO, pL, out);
    } else {
        attn_kern<0><<<dim3(32, NB), 256, 0, stream>>>(ko, qo, vt, nullptr, nullptr, out);
    }
}